// Round 14
// baseline (396.154 us; speedup 1.0000x reference)
//
#include <hip/hip_runtime.h>
#include <hip/hip_bf16.h>

typedef float f32x4 __attribute__((ext_vector_type(4)));
typedef short bf16x8 __attribute__((ext_vector_type(8)));
typedef short short4v __attribute__((ext_vector_type(4)));

constexpr int kB = 2, kN = 32768, kC = 256, kH = 8, kD = 32, kM = 64;
constexpr int kT = kB * kN;  // 65536 token rows

__device__ __forceinline__ float b2f(short s) {
    unsigned u = ((unsigned)(unsigned short)s) << 16;
    return __builtin_bit_cast(float, u);
}
__device__ __forceinline__ short f2b(float f) {
    __hip_bfloat16 h = __float2bfloat16(f);
    return __builtin_bit_cast(short, h);
}
__device__ __forceinline__ float gelu_fast(float x) {
    float x2 = x * x;
    float g2 = x * (2.3022042f + 0.10295342f * x2);
#if __has_builtin(__builtin_amdgcn_exp2f)
    float em = __builtin_amdgcn_exp2f(-g2);
#else
    float em = exp2f(-g2);
#endif
#if __has_builtin(__builtin_amdgcn_rcpf)
    return x * __builtin_amdgcn_rcpf(1.0f + em);
#else
    return x / (1.0f + em);
#endif
}

#if __has_builtin(__builtin_amdgcn_global_load_lds)
__device__ __forceinline__ void gld16(const void* g, void* l) {
    __builtin_amdgcn_global_load_lds((__attribute__((address_space(1))) void*)g,
                                     (__attribute__((address_space(3))) void*)l, 16, 0, 0);
}
#else
__device__ __forceinline__ void gld16(const void* g, void* l) {
    *(bf16x8*)l = *(const bf16x8*)g;
}
#endif

// ---------------- Weight prep: W (K x N f32, row-major) -> Wt (N x K bf16) ----------------
__global__ __launch_bounds__(256) void prep_wt(const float* __restrict__ W,
                                               short* __restrict__ Wt, int K, int N) {
    __shared__ float t[32][33];
    int k0 = blockIdx.x * 32, n0 = blockIdx.y * 32;
    int tx = threadIdx.x & 31, ty = threadIdx.x >> 5;  // 32 x 8
#pragma unroll
    for (int r = 0; r < 32; r += 8)
        t[ty + r][tx] = W[(size_t)(k0 + ty + r) * N + n0 + tx];
    __syncthreads();
#pragma unroll
    for (int r = 0; r < 32; r += 8)
        Wt[(size_t)(n0 + ty + r) * K + k0 + tx] = f2b(t[tx][ty + r]);
}

// ---------------- Fragment-pack: Wt (N x K bf16) -> Wp, MFMA-operand order ----------------
__global__ __launch_bounds__(256) void prep_pack(const short* __restrict__ src,
                                                 short* __restrict__ dst, int K, int KT) {
    int g = blockIdx.x * 256 + threadIdx.x;
    int frag = g >> 6, lane = g & 63;
    int nt = frag / KT, kt = frag - nt * KT;
    const short* s = &src[(size_t)(nt * 16 + (lane & 15)) * K + kt * 32 + (lane >> 4) * 8];
    *(bf16x8*)&dst[(size_t)frag * 512 + lane * 8] = *(const bf16x8*)s;
}

// ---------------- Fold Wx @ Wsl -> Wxsl^T (512 x 256 bf16) + bias bxsl (512 f32) ----------------
__global__ __launch_bounds__(256) void prep_wxsl(const float* __restrict__ Wx,
                                                 const float* __restrict__ Wsl,
                                                 const float* __restrict__ bx,
                                                 const float* __restrict__ bsl,
                                                 short* __restrict__ wxsl_t,
                                                 float* __restrict__ bxsl) {
    int n = blockIdx.x;        // 0..511 = h*64 + m
    int h = n >> 6, m = n & 63;
    int c = threadIdx.x;
    float s = 0.f;
#pragma unroll 8
    for (int dd = 0; dd < 32; ++dd)
        s += Wx[(size_t)c * 256 + h * 32 + dd] * Wsl[dd * 64 + m];
    wxsl_t[(size_t)n * 256 + c] = f2b(s);
    if (c == 0) {
        float bs = bsl[m];
        for (int dd = 0; dd < 32; ++dd) bs += bx[h * 32 + dd] * Wsl[dd * 64 + m];
        bxsl[n] = bs;
    }
}

// ---------------- LayerNorm: wave-per-row, shuffle-only ----------------
template <bool IN_BF16>
__global__ __launch_bounds__(256) void ln_kernel(const void* __restrict__ xin,
                                                 const float* __restrict__ g,
                                                 const float* __restrict__ bb,
                                                 short* __restrict__ out) {
    int row = blockIdx.x * 4 + (threadIdx.x >> 6);
    int lane = threadIdx.x & 63;
    float v[4];
    if constexpr (IN_BF16) {
        short4v s = *((const short4v*)((const short*)xin + (size_t)row * kC) + lane);
#pragma unroll
        for (int j = 0; j < 4; ++j) v[j] = b2f(s[j]);
    } else {
        f32x4 s = *((const f32x4*)((const float*)xin + (size_t)row * kC) + lane);
#pragma unroll
        for (int j = 0; j < 4; ++j) v[j] = s[j];
    }
    float sum = v[0] + v[1] + v[2] + v[3];
#pragma unroll
    for (int o = 32; o; o >>= 1) sum += __shfl_xor(sum, o);
    float mu = sum * (1.0f / 256.0f);
    float c[4];
    float s2 = 0.f;
#pragma unroll
    for (int j = 0; j < 4; ++j) { c[j] = v[j] - mu; s2 += c[j] * c[j]; }
#pragma unroll
    for (int o = 32; o; o >>= 1) s2 += __shfl_xor(s2, o);
    float inv = rsqrtf(s2 * (1.0f / 256.0f) + 1e-5f);
    f32x4 gv = *((const f32x4*)g + lane);
    f32x4 bv = *((const f32x4*)bb + lane);
    short4v o;
#pragma unroll
    for (int j = 0; j < 4; ++j) o[j] = f2b(c[j] * inv * gv[j] + bv[j]);
    *((short4v*)(out + (size_t)row * kC) + lane) = o;
}

// ---------------- MFMA GEMM (Wo): C = A @ Bt^T + bias + res_f32 -> bf16 ----------------
template <int K, int N, int EPI>
__global__ __launch_bounds__(256) void mfma_gemm(const short* __restrict__ A,
                                                 const short* __restrict__ Bt,
                                                 const float* __restrict__ bias,
                                                 const void* __restrict__ res,
                                                 void* __restrict__ Cout) {
    __shared__ __align__(16) short As[128 * 64];
    __shared__ __align__(16) short Bs[128 * 64];
    const int tid = threadIdx.x;
    const int lane = tid & 63;
    const int w = tid >> 6, wr = w >> 1, wc = w & 1;
    const int bm = blockIdx.x * 128, bn = blockIdx.y * 128;
    const int l15 = lane & 15, l16 = lane >> 4;
    f32x4 acc[4][4] = {};
    for (int k0 = 0; k0 < K; k0 += 64) {
        __syncthreads();
#pragma unroll
        for (int l = 0; l < 4; ++l) {
            int li = tid + l * 256;
            int r = li >> 3, s = li & 7;
            int kof = k0 + ((s ^ (r & 7)) << 3);
            gld16(&A[(size_t)(bm + r) * K + kof], &As[li * 8]);
            gld16(&Bt[(size_t)(bn + r) * K + kof], &Bs[li * 8]);
        }
        __syncthreads();
#pragma unroll
        for (int ks = 0; ks < 2; ++ks) {
            bf16x8 av[4], bv[4];
            int q = ks * 4 + l16;
#pragma unroll
            for (int mi = 0; mi < 4; ++mi) {
                int row = wr * 64 + mi * 16 + l15;
                av[mi] = *(const bf16x8*)(&As[row * 64 + ((q ^ (row & 7)) << 3)]);
            }
#pragma unroll
            for (int ni = 0; ni < 4; ++ni) {
                int row = wc * 64 + ni * 16 + l15;
                bv[ni] = *(const bf16x8*)(&Bs[row * 64 + ((q ^ (row & 7)) << 3)]);
            }
#pragma unroll
            for (int mi = 0; mi < 4; ++mi)
#pragma unroll
                for (int ni = 0; ni < 4; ++ni)
                    acc[mi][ni] = __builtin_amdgcn_mfma_f32_16x16x32_bf16(
                        av[mi], bv[ni], acc[mi][ni], 0, 0, 0);
        }
    }
#pragma unroll
    for (int mi = 0; mi < 4; ++mi) {
#pragma unroll
        for (int ni = 0; ni < 4; ++ni) {
            int col = bn + wc * 64 + ni * 16 + l15;
            float bcol = bias[col];
#pragma unroll
            for (int r = 0; r < 4; ++r) {
                size_t row = (size_t)bm + wr * 64 + mi * 16 + l16 * 4 + r;
                float v = acc[mi][ni][r] + bcol;
                size_t off = row * N + col;
                if (EPI == 0) {
                    ((short*)Cout)[off] = f2b(v);
                } else {
                    ((short*)Cout)[off] = f2b(v + ((const float*)res)[off]);
                }
            }
        }
    }
}

// ---------------- Packed-weight projection: [fx | L] = h @ Wfxsl, barrier-free main loop ----------------
// 64 rows/block, 4 waves. Weights fragment-packed (768x256 = 384KB, L2-resident), read
// register-direct (coalesced 1KB/wave). As staged once; after the barrier waves run free.
__global__ __launch_bounds__(256, 3) void proj_packed(const short* __restrict__ h,
                                                      const short* __restrict__ wp,
                                                      const float* __restrict__ bfx,
                                                      const float* __restrict__ bxsl,
                                                      short* __restrict__ fxout,
                                                      short* __restrict__ Lout) {
    __shared__ __align__(16) short As[64 * 256];  // 32 KB; slot q at ((q^(r&7))<<3)
    const int tid = threadIdx.x;
    const int lane = tid & 63, w = tid >> 6;
    const int l15 = lane & 15, l16 = lane >> 4;
    const int bm = blockIdx.x * 64;
#pragma unroll
    for (int l = 0; l < 8; ++l) {
        int li = tid + l * 256;
        int r = li >> 5, s = li & 31;
        gld16(&h[(size_t)(bm + r) * 256 + ((s ^ (r & 7)) << 3)], &As[li * 8]);
    }
    __syncthreads();
#pragma unroll
    for (int pass = 0; pass < 2; ++pass) {
        f32x4 acc[4][6];
#pragma unroll
        for (int tj = 0; tj < 4; ++tj)
#pragma unroll
            for (int cf = 0; cf < 6; ++cf) acc[tj][cf] = f32x4{0.f, 0.f, 0.f, 0.f};
        int cfbase = pass * 24 + w * 6;  // global col-frag base (col = frag*16 + l15)
#pragma unroll
        for (int kf = 0; kf < 8; ++kf) {
            bf16x8 av[4];
#pragma unroll
            for (int tj = 0; tj < 4; ++tj) {
                int row = tj * 16 + l15;
                av[tj] = *(const bf16x8*)&As[row * 256 + (((kf * 4 + l16) ^ (row & 7)) << 3)];
            }
#pragma unroll
            for (int cf = 0; cf < 6; ++cf) {
                bf16x8 bv =
                    *(const bf16x8*)&wp[(size_t)((cfbase + cf) * 8 + kf) * 512 + lane * 8];
#pragma unroll
                for (int tj = 0; tj < 4; ++tj)
                    acc[tj][cf] = __builtin_amdgcn_mfma_f32_16x16x32_bf16(av[tj], bv,
                                                                          acc[tj][cf], 0, 0, 0);
            }
        }
#pragma unroll
        for (int cf = 0; cf < 6; ++cf) {
            int col = (cfbase + cf) * 16 + l15;
            float bc = (col < 256) ? bfx[col] : bxsl[col - 256];
#pragma unroll
            for (int tj = 0; tj < 4; ++tj)
#pragma unroll
                for (int r = 0; r < 4; ++r) {
                    size_t row = (size_t)bm + tj * 16 + l16 * 4 + r;
                    float v = acc[tj][cf][r] + bc;
                    if (col < 256)
                        fxout[row * 256 + col] = f2b(v);
                    else
                        Lout[row * 512 + (col - 256)] = f2b(v);
                }
        }
    }
}

// ---------------- Fused FFN (round-12 version): pipelined, gld16 h2 staging ----------------
__global__ __launch_bounds__(256, 2) void ffn_fused(const short* __restrict__ h2,
                                                    const short* __restrict__ xres,
                                                    const short* __restrict__ w1p,
                                                    const short* __restrict__ w2p,
                                                    const float* __restrict__ b1,
                                                    const float* __restrict__ b2,
                                                    float* __restrict__ out) {
    __shared__ __align__(16) short As[64 * 256];       // 32 KB
    __shared__ __align__(16) short mids[2][64 * 128];  // 2x16 KB
    const int tid = threadIdx.x;
    const int lane = tid & 63, w = tid >> 6;
    const int l15 = lane & 15, l16 = lane >> 4;
    const int bm = blockIdx.x * 64;
#pragma unroll
    for (int l = 0; l < 8; ++l) {
        int li = tid + l * 256;
        int r = li >> 5, s = li & 31;
        gld16(&h2[(size_t)(bm + r) * 256 + ((s ^ (r & 7)) << 3)], &As[li * 8]);
    }
    __syncthreads();
    f32x4 acc2[4][4] = {};
    f32x4 accm[2][4];

#define FFN_GEMM1(jc)                                                                     \
    {                                                                                     \
        _Pragma("unroll") for (int tj = 0; tj < 4; ++tj) {                                \
            accm[0][tj] = f32x4{0.f, 0.f, 0.f, 0.f};                                      \
            accm[1][tj] = f32x4{0.f, 0.f, 0.f, 0.f};                                      \
        }                                                                                 \
        const short* wp0 = &w1p[(size_t)(((jc)*8 + w * 2) * 8) * 512 + lane * 8];         \
        _Pragma("unroll") for (int ks = 0; ks < 8; ++ks) {                                \
            bf16x8 aw0 = *(const bf16x8*)(wp0 + ks * 512);                                \
            bf16x8 aw1 = *(const bf16x8*)(wp0 + (8 + ks) * 512);                          \
            _Pragma("unroll") for (int tj = 0; tj < 4; ++tj) {                            \
                int row = tj * 16 + l15;                                                  \
                int q = ks * 4 + l16;                                                     \
                bf16x8 bh = *(const bf16x8*)&As[row * 256 + ((q ^ (row & 7)) << 3)];      \
                accm[0][tj] =                                                             \
                    __builtin_amdgcn_mfma_f32_16x16x32_bf16(aw0, bh, accm[0][tj], 0, 0, 0); \
                accm[1][tj] =                                                             \
                    __builtin_amdgcn_mfma_f32_16x16x32_bf16(aw1, bh, accm[1][tj], 0, 0, 0); \
            }                                                                             \
        }                                                                                 \
    }

#define FFN_WRITE(jc)                                                                     \
    {                                                                                     \
        _Pragma("unroll") for (int mcf = 0; mcf < 2; ++mcf) {                             \
            int mc0 = w * 32 + mcf * 16 + l16 * 4;                                        \
            f32x4 bc1 = *(const f32x4*)&b1[(jc)*128 + mc0];                               \
            _Pragma("unroll") for (int tj = 0; tj < 4; ++tj) {                            \
                int token = tj * 16 + l15;                                                \
                short4v pk;                                                               \
                _Pragma("unroll") for (int r = 0; r < 4; ++r)                             \
                    pk[r] = f2b(gelu_fast(accm[mcf][tj][r] + bc1[r]));                    \
                *(short4v*)((char*)mids[(jc)&1] + token * 256 +                           \
                            ((mc0 * 2) ^ ((token & 7) << 4))) = pk;                       \
            }                                                                             \
        }                                                                                 \
    }

#define FFN_GEMM2(jc)                                                                     \
    {                                                                                     \
        _Pragma("unroll") for (int ks = 0; ks < 4; ++ks) {                                \
            int q = ks * 4 + l16;                                                         \
            bf16x8 am[4];                                                                 \
            _Pragma("unroll") for (int mi = 0; mi < 4; ++mi) {                            \
                int row = mi * 16 + l15;                                                  \
                am[mi] = *(const bf16x8*)((const char*)mids[(jc)&1] + row * 256 +         \
                                          ((q * 16) ^ ((row & 7) << 4)));                 \
            }                                                                             \
            _Pragma("unroll") for (int ni = 0; ni < 4; ++ni) {                            \
                bf16x8 bv = *(const bf16x8*)&w2p[(size_t)((w * 4 + ni) * 32 + (jc)*4 +    \
                                                          ks) *                           \
                                                     512 +                                \
                                                 lane * 8];                               \
                _Pragma("unroll") for (int mi = 0; mi < 4; ++mi)                          \
                    acc2[mi][ni] = __builtin_amdgcn_mfma_f32_16x16x32_bf16(               \
                        am[mi], bv, acc2[mi][ni], 0, 0, 0);                               \
            }                                                                             \
        }                                                                                 \
    }

    FFN_GEMM1(0);
#pragma unroll
    for (int jc = 0; jc < 8; ++jc) {
        __syncthreads();
        if (jc > 0) FFN_GEMM2(jc - 1);
        FFN_WRITE(jc);
        if (jc < 7) FFN_GEMM1(jc + 1);
    }
    __syncthreads();
    FFN_GEMM2(7);
#undef FFN_GEMM1
#undef FFN_WRITE
#undef FFN_GEMM2

#pragma unroll
    for (int mi = 0; mi < 4; ++mi)
#pragma unroll
        for (int ni = 0; ni < 4; ++ni) {
            int col = w * 64 + ni * 16 + l15;
            float bc2 = b2[col];
#pragma unroll
            for (int r = 0; r < 4; ++r) {
                size_t row = (size_t)bm + mi * 16 + l16 * 4 + r;
                out[row * 256 + col] = acc2[mi][ni][r] + bc2 + b2f(xres[row * 256 + col]);
            }
        }
}

// ---------------- Fused slice routing: softmax from L, then stoken = sw^T @ fx via MFMA ----------------
__global__ __launch_bounds__(256) void fused_slice(const short* __restrict__ L,
                                                   const short* __restrict__ fx,
                                                   const float* __restrict__ temp,
                                                   float* __restrict__ stoken,
                                                   float* __restrict__ snorm) {
    int h = blockIdx.y;
    int t0g = blockIdx.x * 2048;
    int b = t0g >> 15;
    int tid = threadIdx.x;
    int lane = tid & 63, w = tid >> 6;
    int l15 = lane & 15, l16 = lane >> 4;
    __shared__ __align__(16) char smem[57344];
    float inv_t = 1.0f / fmaxf(temp[h], 0.1f);
    const int tt2 = tid * 2;
#pragma unroll
    for (int r = 0; r < 16; ++r) {
        int row = 32 + r;
        *(short*)(smem + 32768 + row * 512 + (tt2 ^ ((row & 7) << 4))) =
            (r == 0) ? (short)0x3F80 : (short)0;
    }
    f32x4 acc[4][3] = {};
    const int swz = (l15 & 7) << 4;
    const int abase = l15 * 512;
    for (int sub = 0; sub < 8; ++sub) {
        __syncthreads();
        int t = t0g + sub * 256 + tid;
        float lg[64];
        const short* Lp = &L[(size_t)t * 512 + h * 64];
#pragma unroll
        for (int mv = 0; mv < 8; ++mv) {
            bf16x8 v = *(const bf16x8*)(Lp + mv * 8);
#pragma unroll
            for (int j = 0; j < 8; ++j) lg[mv * 8 + j] = b2f(v[j]) * inv_t;
        }
        float mx = -1e30f;
#pragma unroll
        for (int m = 0; m < 64; ++m) mx = fmaxf(mx, lg[m]);
        float sum = 0.f;
#pragma unroll
        for (int m = 0; m < 64; ++m) { lg[m] = expf(lg[m] - mx); sum += lg[m]; }
        float inv = 1.0f / sum;
#pragma unroll
        for (int m = 0; m < 64; ++m)
            *(short*)(smem + m * 512 + (tt2 ^ ((m & 7) << 4))) = f2b(lg[m] * inv);
        const short* fxp = &fx[(size_t)t * 256 + h * 32];
#pragma unroll
        for (int mv = 0; mv < 4; ++mv) {
            bf16x8 v = *(const bf16x8*)(fxp + mv * 8);
#pragma unroll
            for (int j = 0; j < 8; ++j)
                *(short*)(smem + 32768 + (mv * 8 + j) * 512 + (tt2 ^ (j << 4))) = v[j];
        }
        __syncthreads();
#pragma unroll
        for (int ks = 0; ks < 2; ++ks) {
            int off = ((w * 8 + ks * 4 + l16) * 16) ^ swz;
            bf16x8 a0 = *(const bf16x8*)(smem + abase + off);
            bf16x8 a1 = *(const bf16x8*)(smem + abase + 8192 + off);
            bf16x8 a2 = *(const bf16x8*)(smem + abase + 16384 + off);
            bf16x8 a3 = *(const bf16x8*)(smem + abase + 24576 + off);
            bf16x8 b0 = *(const bf16x8*)(smem + 32768 + abase + off);
            bf16x8 b1 = *(const bf16x8*)(smem + 32768 + abase + 8192 + off);
            bf16x8 b2v = *(const bf16x8*)(smem + 32768 + abase + 16384 + off);
            acc[0][0] = __builtin_amdgcn_mfma_f32_16x16x32_bf16(a0, b0, acc[0][0], 0, 0, 0);
            acc[0][1] = __builtin_amdgcn_mfma_f32_16x16x32_bf16(a0, b1, acc[0][1], 0, 0, 0);
            acc[0][2] = __builtin_amdgcn_mfma_f32_16x16x32_bf16(a0, b2v, acc[0][2], 0, 0, 0);
            acc[1][0] = __builtin_amdgcn_mfma_f32_16x16x32_bf16(a1, b0, acc[1][0], 0, 0, 0);
            acc[1][1] = __builtin_amdgcn_mfma_f32_16x16x32_bf16(a1, b1, acc[1][1], 0, 0, 0);
            acc[1][2] = __builtin_amdgcn_mfma_f32_16x16x32_bf16(a1, b2v, acc[1][2], 0, 0, 0);
            acc[2][0] = __builtin_amdgcn_mfma_f32_16x16x32_bf16(a2, b0, acc[2][0], 0, 0, 0);
            acc[2][1] = __builtin_amdgcn_mfma_f32_16x16x32_bf16(a2, b1, acc[2][1], 0, 0, 0);
            acc[2][2] = __builtin_amdgcn_mfma_f32_16x16x32_bf16(a2, b2v, acc[2][2], 0, 0, 0);
            acc[3][0] = __builtin_amdgcn_mfma_f32_16x16x32_bf16(a3, b0, acc[3][0], 0, 0, 0);
            acc[3][1] = __builtin_amdgcn_mfma_f32_16x16x32_bf16(a3, b1, acc[3][1], 0, 0, 0);
            acc[3][2] = __builtin_amdgcn_mfma_f32_16x16x32_bf16(a3, b2v, acc[3][2], 0, 0, 0);
        }
    }
    __syncthreads();
    float* red = (float*)smem;  // [4 waves][64 m][48 n]
#pragma unroll
    for (int mi = 0; mi < 4; ++mi)
#pragma unroll
        for (int ni = 0; ni < 3; ++ni)
#pragma unroll
            for (int r = 0; r < 4; ++r)
                red[w * 3072 + (mi * 16 + l16 * 4 + r) * 48 + ni * 16 + l15] =
                    acc[mi][ni][r];
    __syncthreads();
    for (int e = tid; e < 3072; e += 256) {
        float s = red[e] + red[3072 + e] + red[6144 + e] + red[9216 + e];
        int m = e / 48, n = e - m * 48;
        if (n < 32)
            atomicAdd(&stoken[(size_t)((b * 8 + h) * 64 + m) * 32 + n], s);
        else if (n == 32)
            atomicAdd(&snorm[(b * 8 + h) * 64 + m], s);
    }
}

// ---------------- Tiny M=64 attention per (b,h): 256 threads, LDS-staged ----------------
__global__ __launch_bounds__(256) void slice_attn_kernel(const float* __restrict__ stoken,
                                                         const float* __restrict__ snorm,
                                                         const float* __restrict__ Wq,
                                                         const float* __restrict__ Wk,
                                                         const float* __restrict__ Wv,
                                                         float* __restrict__ oslice) {
    int bh = blockIdx.x;
    int tid = threadIdx.x;
    int m = tid & 63, grp = tid >> 6;  // 4 groups
    __shared__ float st_s[64][33];
    __shared__ float q_s[64][33];
    __shared__ float k_s[64][33];
    __shared__ float v_s[64][33];
    __shared__ float w_s[3][32][32];
    __shared__ float sc_s[64][65];
    __shared__ float nrm_s[64];
    for (int i = tid; i < 3072; i += 256) {
        const float* W = (i < 1024) ? Wq : (i < 2048 ? Wk : Wv);
        int r = i & 1023;
        w_s[i >> 10][r >> 5][r & 31] = W[r];
    }
    if (tid < 64) nrm_s[tid] = 1.0f / fmaxf(snorm[bh * 64 + tid], 1e-5f);
    for (int i = tid; i < 512; i += 256) {
        int mm = i >> 3, dq = (i & 7) << 2;
        f32x4 v = *(const f32x4*)&stoken[(size_t)bh * 2048 + mm * 32 + dq];
        *(f32x4*)&st_s[mm][dq] = v;
    }
    __syncthreads();
    {
        int d0 = grp * 8;
        float qr[8] = {}, kr[8] = {}, vr[8] = {};
#pragma unroll
        for (int dd = 0; dd < 32; ++dd) {
            float s = st_s[m][dd];
#pragma unroll
            for (int j = 0; j < 8; ++j) {
                qr[j] += s * w_s[0][dd][d0 + j];
                kr[j] += s * w_s[1][dd][d0 + j];
                vr[j] += s * w_s[2][dd][d0 + j];
            }
        }
        float nm = nrm_s[m];
#pragma unroll
        for (int j = 0; j < 8; ++j) {
            q_s[m][d0 + j] = qr[j] * nm;
            k_s[m][d0 + j] = kr[j] * nm;
            v_s[m][d0 + j] = vr[j] * nm;
        }
    }
    __syncthreads();
    {
#pragma unroll
        for (int gg = 0; gg < 16; ++gg) {
            int g = grp * 16 + gg;
            float s = 0.f;
#pragma unroll
            for (int dd = 0; dd < 32; ++dd) s += q_s[m][dd] * k_s[g][dd];
            sc_s[m][g] = s * 0.17677669529663687f;
        }
    }
    __syncthreads();
    if (tid < 64) {
        float mx = -1e30f;
#pragma unroll
        for (int g = 0; g < 64; ++g) mx = fmaxf(mx, sc_s[tid][g]);
        float sum = 0.f;
#pragma unroll
        for (int g = 0; g < 64; ++g) {
            float e = expf(sc_s[tid][g] - mx);
            sc_s[tid][g] = e;
            sum += e;
        }
        float inv = 1.0f / sum;
#pragma unroll
        for (int g = 0; g < 64; ++g) sc_s[tid][g] *= inv;
    }
    __syncthreads();
    {
        int d0 = grp * 8;
        float o[8] = {};
#pragma unroll
        for (int g = 0; g < 64; ++g) {
            float p = sc_s[m][g];
#pragma unroll
            for (int j = 0; j < 8; ++j) o[j] += p * v_s[g][d0 + j];
        }
#pragma unroll
        for (int j = 0; j < 8; ++j)
            oslice[(size_t)bh * 2048 + m * 32 + d0 + j] = o[j];
    }
}

// ---------------- Scatter: y = sw @ oslice via MFMA (sw recomputed from L) ----------------
__global__ __launch_bounds__(256) void scatter_mfma(const short* __restrict__ L,
                                                    const float* __restrict__ oslice,
                                                    const float* __restrict__ temp,
                                                    short* __restrict__ y) {
    int h = blockIdx.y;
    int t0 = blockIdx.x * 256;
    int b = t0 >> 15;
    int tid = threadIdx.x;
    int lane = tid & 63, w = tid >> 6;
    int l15 = lane & 15, l16 = lane >> 4;
    __shared__ __align__(16) char smem[36864];
    float inv_t = 1.0f / fmaxf(temp[h], 0.1f);
    const float* osp = &oslice[(size_t)(b * 8 + h) * 2048];
    for (int i = tid; i < 2048; i += 256) {
        int m = i >> 5, d = i & 31;
        *(short*)(smem + 32768 + d * 128 + ((2 * m) ^ ((d & 7) << 4))) = f2b(osp[m * 32 + d]);
    }
    float lg[64];
    const short* Lp = &L[(size_t)(t0 + tid) * 512 + h * 64];
#pragma unroll
    for (int mv = 0; mv < 8; ++mv) {
        bf16x8 v = *(const bf16x8*)(Lp + mv * 8);
#pragma unroll
        for (int j = 0; j < 8; ++j) lg[mv * 8 + j] = b2f(v[j]) * inv_t;
    }
    float mx = -1e30f;
#pragma unroll
    for (int m = 0; m < 64; ++m) mx = fmaxf(mx, lg[m]);
    float sum = 0.f;
#pragma unroll
    for (int m = 0; m < 64; ++m) { lg[m] = expf(lg[m] - mx); sum += lg[m]; }
    float inv = 1.0f / sum;
    int tswz = (tid & 7) << 4;
#pragma unroll
    for (int jm = 0; jm < 8; ++jm) {
        bf16x8 o;
#pragma unroll
        for (int j = 0; j < 8; ++j) o[j] = f2b(lg[jm * 8 + j] * inv);
        *(bf16x8*)(smem + tid * 128 + ((jm * 16) ^ tswz)) = o;
    }
    __syncthreads();
    const int swz = (l15 & 7) << 4;
    f32x4 acc[4][2] = {};
#pragma unroll
    for (int ks = 0; ks < 2; ++ks) {
        int off = ((ks * 4 + l16) * 16) ^ swz;
        bf16x8 b0 = *(const bf16x8*)(smem + 32768 + l15 * 128 + off);
        bf16x8 b1 = *(const bf16x8*)(smem + 32768 + (16 + l15) * 128 + off);
#pragma unroll
        for (int i = 0; i < 4; ++i) {
            bf16x8 a = *(const bf16x8*)(smem + (w * 64 + i * 16 + l15) * 128 + off);
            acc[i][0] = __builtin_amdgcn_mfma_f32_16x16x32_bf16(a, b0, acc[i][0], 0, 0, 0);
            acc[i][1] = __builtin_amdgcn_mfma_f32_16x16x32_bf16(a, b1, acc[i][1], 0, 0, 0);
        }
    }
#pragma unroll
    for (int i = 0; i < 4; ++i)
#pragma unroll
        for (int ni = 0; ni < 2; ++ni)
#pragma unroll
            for (int r = 0; r < 4; ++r) {
                int tr = w * 64 + i * 16 + l16 * 4 + r;
                y[(size_t)(t0 + tr) * 256 + h * 32 + ni * 16 + l15] = f2b(acc[i][ni][r]);
            }
}

extern "C" void kernel_launch(void* const* d_in, const int* in_sizes, int n_in,
                              void* d_out, int out_size, void* d_ws, size_t ws_size,
                              hipStream_t stream) {
    (void)in_sizes; (void)n_in; (void)out_size; (void)ws_size;
    const float* x    = (const float*)d_in[0];
    const float* ln1g = (const float*)d_in[1];
    const float* ln1b = (const float*)d_in[2];
    const float* Wfx  = (const float*)d_in[3];
    const float* bfx  = (const float*)d_in[4];
    const float* Wx   = (const float*)d_in[5];
    const float* bx   = (const float*)d_in[6];
    const float* Wsl  = (const float*)d_in[7];
    const float* bsl  = (const float*)d_in[8];
    const float* temp = (const float*)d_in[9];
    const float* Wq   = (const float*)d_in[10];
    const float* Wk   = (const float*)d_in[11];
    const float* Wv   = (const float*)d_in[12];
    const float* Wo   = (const float*)d_in[13];
    const float* bo   = (const float*)d_in[14];
    const float* ln2g = (const float*)d_in[15];
    const float* ln2b = (const float*)d_in[16];
    const float* W1   = (const float*)d_in[17];
    const float* b1   = (const float*)d_in[18];
    const float* W2   = (const float*)d_in[19];
    const float* b2   = (const float*)d_in[20];
    float* out = (float*)d_out;

    constexpr size_t SLOT = (size_t)kT * kC * 2;  // 32MB
    char* ws = (char*)d_ws;
    short* S0 = (short*)(ws);             // h -> y -> h2
    short* S1 = (short*)(ws + SLOT);      // fx -> xres
    char*  S3 = ws + 3 * SLOT;
    short* wfx_t   = (short*)(S3);                // 256 x 256
    short* wxsl_t  = (short*)(S3 + 131072);       // 512 x 256 (contiguous -> 768x256)
    short* wo_t    = (short*)(S3 + 393216);       // 256 x 256
    short* w1_t    = (short*)(S3 + 524288);       // 1024 x 256
    short* w2_t    = (short*)(S3 + 1048576);      // 256 x 1024
    float* bxsl    = (float*)(S3 + 1572864);      // 512
    float* stoken  = (float*)(S3 + 1574912);      // (B,H,M,D)
    float* snorm   = (float*)(S3 + 1705984);      // (B,H,M)
    float* oslice  = (float*)(S3 + 1710080);      // (B,H,M,D)
    short* w1p     = (short*)(S3 + 1841152);      // packed 1024x256
    short* w2p     = (short*)(S3 + 2365440);      // packed 256x1024
    short* wfxsl_p = (short*)(S3 + 2889728);      // packed 768x256 (786432 B)

    short* h    = S0;
    short* fx   = S1;
    short* y    = S0;
    short* xres = S1;
    short* h2   = S0;
    short* Lbuf = (short*)d_out;  // T x 512 bf16 logits (dead before ffn_fused writes d_out)

    // 0. weight prep (+ fragment packing)
    prep_wt<<<dim3(8, 8), 256, 0, stream>>>(Wfx, wfx_t, 256, 256);
    prep_wt<<<dim3(8, 8), 256, 0, stream>>>(Wo, wo_t, 256, 256);
    prep_wt<<<dim3(8, 32), 256, 0, stream>>>(W1, w1_t, 256, 1024);
    prep_wt<<<dim3(32, 8), 256, 0, stream>>>(W2, w2_t, 1024, 256);
    prep_wxsl<<<512, 256, 0, stream>>>(Wx, Wsl, bx, bsl, wxsl_t, bxsl);
    prep_pack<<<128, 256, 0, stream>>>(w1_t, w1p, 256, 8);       // N=1024, KT=8
    prep_pack<<<128, 256, 0, stream>>>(w2_t, w2p, 1024, 32);     // N=256,  KT=32
    prep_pack<<<96, 256, 0, stream>>>(wfx_t, wfxsl_p, 256, 8);   // N=768,  KT=8
    hipMemsetAsync(stoken, 0, 131072 + 4096, stream);

    // 1. LN1: x -> h
    ln_kernel<false><<<kT / 4, 256, 0, stream>>>(x, ln1g, ln1b, h);
    // 2. packed projection: [fx | L] = h @ Wfxsl (barrier-free main loop)
    proj_packed<<<kT / 64, 256, 0, stream>>>(h, wfxsl_p, bfx, bxsl, fx, Lbuf);
    // 3. fused slice routing
    fused_slice<<<dim3(kT / 2048, kH), 256, 0, stream>>>(Lbuf, fx, temp, stoken, snorm);
    // 4. tiny attention over M slices
    slice_attn_kernel<<<kB * kH, 256, 0, stream>>>(stoken, snorm, Wq, Wk, Wv, oslice);
    // 5. scatter back to tokens via MFMA -> y
    scatter_mfma<<<dim3(kT / 256, kH), 256, 0, stream>>>(Lbuf, oslice, temp, y);
    // 6. Wo projection + residual(x f32) -> xres
    mfma_gemm<256, 256, 1><<<dim3(kT / 128, 2), 256, 0, stream>>>(y, wo_t, bo, x, xres);
    // 7. LN2: xres -> h2
    ln_kernel<true><<<kT / 4, 256, 0, stream>>>(xres, ln2g, ln2b, h2);
    // 8. fused FFN (round-12 pipelined version)
    ffn_fused<<<kT / 64, 256, 0, stream>>>(h2, xres, w1p, w2p, b1, b2, out);
}

// Round 15
// 304.676 us; speedup vs baseline: 1.3002x; 1.3002x over previous
//
#include <hip/hip_runtime.h>
#include <hip/hip_bf16.h>

typedef float f32x4 __attribute__((ext_vector_type(4)));
typedef short bf16x8 __attribute__((ext_vector_type(8)));
typedef short short4v __attribute__((ext_vector_type(4)));

constexpr int kB = 2, kN = 32768, kC = 256, kH = 8, kD = 32, kM = 64;
constexpr int kT = kB * kN;  // 65536 token rows

__device__ __forceinline__ float b2f(short s) {
    unsigned u = ((unsigned)(unsigned short)s) << 16;
    return __builtin_bit_cast(float, u);
}
__device__ __forceinline__ short f2b(float f) {
    __hip_bfloat16 h = __float2bfloat16(f);
    return __builtin_bit_cast(short, h);
}
__device__ __forceinline__ float gelu_fast(float x) {
    float x2 = x * x;
    float g2 = x * (2.3022042f + 0.10295342f * x2);
#if __has_builtin(__builtin_amdgcn_exp2f)
    float em = __builtin_amdgcn_exp2f(-g2);
#else
    float em = exp2f(-g2);
#endif
#if __has_builtin(__builtin_amdgcn_rcpf)
    return x * __builtin_amdgcn_rcpf(1.0f + em);
#else
    return x / (1.0f + em);
#endif
}

#if __has_builtin(__builtin_amdgcn_global_load_lds)
__device__ __forceinline__ void gld16(const void* g, void* l) {
    __builtin_amdgcn_global_load_lds((__attribute__((address_space(1))) void*)g,
                                     (__attribute__((address_space(3))) void*)l, 16, 0, 0);
}
#else
__device__ __forceinline__ void gld16(const void* g, void* l) {
    *(bf16x8*)l = *(const bf16x8*)g;
}
#endif

// ---------------- Weight prep: W (K x N f32, row-major) -> Wt (N x K bf16) ----------------
__global__ __launch_bounds__(256) void prep_wt(const float* __restrict__ W,
                                               short* __restrict__ Wt, int K, int N) {
    __shared__ float t[32][33];
    int k0 = blockIdx.x * 32, n0 = blockIdx.y * 32;
    int tx = threadIdx.x & 31, ty = threadIdx.x >> 5;  // 32 x 8
#pragma unroll
    for (int r = 0; r < 32; r += 8)
        t[ty + r][tx] = W[(size_t)(k0 + ty + r) * N + n0 + tx];
    __syncthreads();
#pragma unroll
    for (int r = 0; r < 32; r += 8)
        Wt[(size_t)(n0 + ty + r) * K + k0 + tx] = f2b(t[tx][ty + r]);
}

// ---------------- Fragment-pack: Wt (N x K bf16) -> Wp, MFMA-operand order ----------------
__global__ __launch_bounds__(256) void prep_pack(const short* __restrict__ src,
                                                 short* __restrict__ dst, int K, int KT) {
    int g = blockIdx.x * 256 + threadIdx.x;
    int frag = g >> 6, lane = g & 63;
    int nt = frag / KT, kt = frag - nt * KT;
    const short* s = &src[(size_t)(nt * 16 + (lane & 15)) * K + kt * 32 + (lane >> 4) * 8];
    *(bf16x8*)&dst[(size_t)frag * 512 + lane * 8] = *(const bf16x8*)s;
}

// ---------------- Fold Wx @ Wsl -> Wxsl^T (512 x 256 bf16) + bias bxsl (512 f32) ----------------
__global__ __launch_bounds__(256) void prep_wxsl(const float* __restrict__ Wx,
                                                 const float* __restrict__ Wsl,
                                                 const float* __restrict__ bx,
                                                 const float* __restrict__ bsl,
                                                 short* __restrict__ wxsl_t,
                                                 float* __restrict__ bxsl) {
    int n = blockIdx.x;        // 0..511 = h*64 + m
    int h = n >> 6, m = n & 63;
    int c = threadIdx.x;
    float s = 0.f;
#pragma unroll 8
    for (int dd = 0; dd < 32; ++dd)
        s += Wx[(size_t)c * 256 + h * 32 + dd] * Wsl[dd * 64 + m];
    wxsl_t[(size_t)n * 256 + c] = f2b(s);
    if (c == 0) {
        float bs = bsl[m];
        for (int dd = 0; dd < 32; ++dd) bs += bx[h * 32 + dd] * Wsl[dd * 64 + m];
        bxsl[n] = bs;
    }
}

// ---------------- LayerNorm: wave-per-row, shuffle-only ----------------
template <bool IN_BF16>
__global__ __launch_bounds__(256) void ln_kernel(const void* __restrict__ xin,
                                                 const float* __restrict__ g,
                                                 const float* __restrict__ bb,
                                                 short* __restrict__ out) {
    int row = blockIdx.x * 4 + (threadIdx.x >> 6);
    int lane = threadIdx.x & 63;
    float v[4];
    if constexpr (IN_BF16) {
        short4v s = *((const short4v*)((const short*)xin + (size_t)row * kC) + lane);
#pragma unroll
        for (int j = 0; j < 4; ++j) v[j] = b2f(s[j]);
    } else {
        f32x4 s = *((const f32x4*)((const float*)xin + (size_t)row * kC) + lane);
#pragma unroll
        for (int j = 0; j < 4; ++j) v[j] = s[j];
    }
    float sum = v[0] + v[1] + v[2] + v[3];
#pragma unroll
    for (int o = 32; o; o >>= 1) sum += __shfl_xor(sum, o);
    float mu = sum * (1.0f / 256.0f);
    float c[4];
    float s2 = 0.f;
#pragma unroll
    for (int j = 0; j < 4; ++j) { c[j] = v[j] - mu; s2 += c[j] * c[j]; }
#pragma unroll
    for (int o = 32; o; o >>= 1) s2 += __shfl_xor(s2, o);
    float inv = rsqrtf(s2 * (1.0f / 256.0f) + 1e-5f);
    f32x4 gv = *((const f32x4*)g + lane);
    f32x4 bv = *((const f32x4*)bb + lane);
    short4v o;
#pragma unroll
    for (int j = 0; j < 4; ++j) o[j] = f2b(c[j] * inv * gv[j] + bv[j]);
    *((short4v*)(out + (size_t)row * kC) + lane) = o;
}

// ---------------- Wo GEMM: C = A @ Bt^T + bias + res_f32 -> bf16, LDS-coalesced writes ----------------
__global__ __launch_bounds__(256) void wo_gemm(const short* __restrict__ A,
                                               const short* __restrict__ Bt,
                                               const float* __restrict__ bias,
                                               const float* __restrict__ res,
                                               short* __restrict__ Cout) {
    __shared__ __align__(16) short smem[2 * 128 * 64];  // As | Bs, reused as 32KB C-stage
    short* As = smem;
    short* Bs = smem + 128 * 64;
    const int tid = threadIdx.x;
    const int lane = tid & 63;
    const int w = tid >> 6, wr = w >> 1, wc = w & 1;
    const int bm = blockIdx.x * 128, bn = blockIdx.y * 128;
    const int l15 = lane & 15, l16 = lane >> 4;
    f32x4 acc[4][4] = {};
    for (int k0 = 0; k0 < 256; k0 += 64) {
        __syncthreads();
#pragma unroll
        for (int l = 0; l < 4; ++l) {
            int li = tid + l * 256;
            int r = li >> 3, s = li & 7;
            int kof = k0 + ((s ^ (r & 7)) << 3);
            gld16(&A[(size_t)(bm + r) * 256 + kof], &As[li * 8]);
            gld16(&Bt[(size_t)(bn + r) * 256 + kof], &Bs[li * 8]);
        }
        __syncthreads();
#pragma unroll
        for (int ks = 0; ks < 2; ++ks) {
            bf16x8 av[4], bv[4];
            int q = ks * 4 + l16;
#pragma unroll
            for (int mi = 0; mi < 4; ++mi) {
                int row = wr * 64 + mi * 16 + l15;
                av[mi] = *(const bf16x8*)(&As[row * 64 + ((q ^ (row & 7)) << 3)]);
            }
#pragma unroll
            for (int ni = 0; ni < 4; ++ni) {
                int row = wc * 64 + ni * 16 + l15;
                bv[ni] = *(const bf16x8*)(&Bs[row * 64 + ((q ^ (row & 7)) << 3)]);
            }
#pragma unroll
            for (int mi = 0; mi < 4; ++mi)
#pragma unroll
                for (int ni = 0; ni < 4; ++ni)
                    acc[mi][ni] = __builtin_amdgcn_mfma_f32_16x16x32_bf16(
                        av[mi], bv[ni], acc[mi][ni], 0, 0, 0);
        }
    }
    __syncthreads();  // As/Bs reads done; reuse as C-stage
    char* cs = (char*)smem;  // [128 row][256 B], byte = row*256 + ((col*2) ^ ((row&7)<<4))
#pragma unroll
    for (int mi = 0; mi < 4; ++mi)
#pragma unroll
        for (int ni = 0; ni < 4; ++ni) {
            int col = wc * 64 + ni * 16 + l15;
            float bcol = bias[bn + col];
#pragma unroll
            for (int r = 0; r < 4; ++r) {
                int row = wr * 64 + mi * 16 + l16 * 4 + r;
                float v = acc[mi][ni][r] + bcol +
                          res[(size_t)(bm + row) * 256 + bn + col];
                *(short*)(cs + row * 256 + ((col * 2) ^ ((row & 7) << 4))) = f2b(v);
            }
        }
    __syncthreads();
#pragma unroll
    for (int pass = 0; pass < 8; ++pass) {
        int row = pass * 16 + (tid >> 4), chunk = tid & 15;
        bf16x8 v = *(const bf16x8*)(cs + row * 256 + ((chunk * 16) ^ ((row & 7) << 4)));
        *(bf16x8*)&Cout[(size_t)(bm + row) * 256 + bn + chunk * 8] = v;
    }
}

// ---------------- Dual projection [fx | L] = h @ [wfx;wxsl]^T, LDS-coalesced writes ----------------
__global__ __launch_bounds__(256) void proj_dual(const short* __restrict__ A,
                                                 const short* __restrict__ Bt,
                                                 const float* __restrict__ bfx,
                                                 const float* __restrict__ bxsl,
                                                 short* __restrict__ fxout,
                                                 short* __restrict__ Lout) {
    __shared__ __align__(16) short smem[2 * 128 * 64];  // As | Bs -> C-stage
    short* As = smem;
    short* Bs = smem + 128 * 64;
    const int tid = threadIdx.x;
    const int lane = tid & 63;
    const int w = tid >> 6, wr = w >> 1, wc = w & 1;
    const int bm = blockIdx.x * 128, bn = blockIdx.y * 128;
    const int l15 = lane & 15, l16 = lane >> 4;
    f32x4 acc[4][4] = {};
    for (int k0 = 0; k0 < 256; k0 += 64) {
        __syncthreads();
#pragma unroll
        for (int l = 0; l < 4; ++l) {
            int li = tid + l * 256;
            int r = li >> 3, s = li & 7;
            int kof = k0 + ((s ^ (r & 7)) << 3);
            gld16(&A[(size_t)(bm + r) * 256 + kof], &As[li * 8]);
            gld16(&Bt[(size_t)(bn + r) * 256 + kof], &Bs[li * 8]);
        }
        __syncthreads();
#pragma unroll
        for (int ks = 0; ks < 2; ++ks) {
            bf16x8 av[4], bv[4];
            int q = ks * 4 + l16;
#pragma unroll
            for (int mi = 0; mi < 4; ++mi) {
                int row = wr * 64 + mi * 16 + l15;
                av[mi] = *(const bf16x8*)(&As[row * 64 + ((q ^ (row & 7)) << 3)]);
            }
#pragma unroll
            for (int ni = 0; ni < 4; ++ni) {
                int row = wc * 64 + ni * 16 + l15;
                bv[ni] = *(const bf16x8*)(&Bs[row * 64 + ((q ^ (row & 7)) << 3)]);
            }
#pragma unroll
            for (int mi = 0; mi < 4; ++mi)
#pragma unroll
                for (int ni = 0; ni < 4; ++ni)
                    acc[mi][ni] = __builtin_amdgcn_mfma_f32_16x16x32_bf16(
                        av[mi], bv[ni], acc[mi][ni], 0, 0, 0);
        }
    }
    __syncthreads();
    char* cs = (char*)smem;
#pragma unroll
    for (int mi = 0; mi < 4; ++mi)
#pragma unroll
        for (int ni = 0; ni < 4; ++ni) {
            int col = wc * 64 + ni * 16 + l15;
            int gcol = bn + col;
            float bcol = (gcol < 256) ? bfx[gcol] : bxsl[gcol - 256];
#pragma unroll
            for (int r = 0; r < 4; ++r) {
                int row = wr * 64 + mi * 16 + l16 * 4 + r;
                *(short*)(cs + row * 256 + ((col * 2) ^ ((row & 7) << 4))) =
                    f2b(acc[mi][ni][r] + bcol);
            }
        }
    __syncthreads();
    const bool isfx = (bn < 256);
#pragma unroll
    for (int pass = 0; pass < 8; ++pass) {
        int row = pass * 16 + (tid >> 4), chunk = tid & 15;
        bf16x8 v = *(const bf16x8*)(cs + row * 256 + ((chunk * 16) ^ ((row & 7) << 4)));
        if (isfx)
            *(bf16x8*)&fxout[(size_t)(bm + row) * 256 + bn + chunk * 8] = v;
        else
            *(bf16x8*)&Lout[(size_t)(bm + row) * 512 + (bn - 256) + chunk * 8] = v;
    }
}

// ---------------- Fused FFN (round-12 pipelined version) ----------------
__global__ __launch_bounds__(256, 2) void ffn_fused(const short* __restrict__ h2,
                                                    const short* __restrict__ xres,
                                                    const short* __restrict__ w1p,
                                                    const short* __restrict__ w2p,
                                                    const float* __restrict__ b1,
                                                    const float* __restrict__ b2,
                                                    float* __restrict__ out) {
    __shared__ __align__(16) short As[64 * 256];       // 32 KB
    __shared__ __align__(16) short mids[2][64 * 128];  // 2x16 KB
    const int tid = threadIdx.x;
    const int lane = tid & 63, w = tid >> 6;
    const int l15 = lane & 15, l16 = lane >> 4;
    const int bm = blockIdx.x * 64;
#pragma unroll
    for (int l = 0; l < 8; ++l) {
        int li = tid + l * 256;
        int r = li >> 5, s = li & 31;
        gld16(&h2[(size_t)(bm + r) * 256 + ((s ^ (r & 7)) << 3)], &As[li * 8]);
    }
    __syncthreads();
    f32x4 acc2[4][4] = {};
    f32x4 accm[2][4];

#define FFN_GEMM1(jc)                                                                     \
    {                                                                                     \
        _Pragma("unroll") for (int tj = 0; tj < 4; ++tj) {                                \
            accm[0][tj] = f32x4{0.f, 0.f, 0.f, 0.f};                                      \
            accm[1][tj] = f32x4{0.f, 0.f, 0.f, 0.f};                                      \
        }                                                                                 \
        const short* wp0 = &w1p[(size_t)(((jc)*8 + w * 2) * 8) * 512 + lane * 8];         \
        _Pragma("unroll") for (int ks = 0; ks < 8; ++ks) {                                \
            bf16x8 aw0 = *(const bf16x8*)(wp0 + ks * 512);                                \
            bf16x8 aw1 = *(const bf16x8*)(wp0 + (8 + ks) * 512);                          \
            _Pragma("unroll") for (int tj = 0; tj < 4; ++tj) {                            \
                int row = tj * 16 + l15;                                                  \
                int q = ks * 4 + l16;                                                     \
                bf16x8 bh = *(const bf16x8*)&As[row * 256 + ((q ^ (row & 7)) << 3)];      \
                accm[0][tj] =                                                             \
                    __builtin_amdgcn_mfma_f32_16x16x32_bf16(aw0, bh, accm[0][tj], 0, 0, 0); \
                accm[1][tj] =                                                             \
                    __builtin_amdgcn_mfma_f32_16x16x32_bf16(aw1, bh, accm[1][tj], 0, 0, 0); \
            }                                                                             \
        }                                                                                 \
    }

#define FFN_WRITE(jc)                                                                     \
    {                                                                                     \
        _Pragma("unroll") for (int mcf = 0; mcf < 2; ++mcf) {                             \
            int mc0 = w * 32 + mcf * 16 + l16 * 4;                                        \
            f32x4 bc1 = *(const f32x4*)&b1[(jc)*128 + mc0];                               \
            _Pragma("unroll") for (int tj = 0; tj < 4; ++tj) {                            \
                int token = tj * 16 + l15;                                                \
                short4v pk;                                                               \
                _Pragma("unroll") for (int r = 0; r < 4; ++r)                             \
                    pk[r] = f2b(gelu_fast(accm[mcf][tj][r] + bc1[r]));                    \
                *(short4v*)((char*)mids[(jc)&1] + token * 256 +                           \
                            ((mc0 * 2) ^ ((token & 7) << 4))) = pk;                       \
            }                                                                             \
        }                                                                                 \
    }

#define FFN_GEMM2(jc)                                                                     \
    {                                                                                     \
        _Pragma("unroll") for (int ks = 0; ks < 4; ++ks) {                                \
            int q = ks * 4 + l16;                                                         \
            bf16x8 am[4];                                                                 \
            _Pragma("unroll") for (int mi = 0; mi < 4; ++mi) {                            \
                int row = mi * 16 + l15;                                                  \
                am[mi] = *(const bf16x8*)((const char*)mids[(jc)&1] + row * 256 +         \
                                          ((q * 16) ^ ((row & 7) << 4)));                 \
            }                                                                             \
            _Pragma("unroll") for (int ni = 0; ni < 4; ++ni) {                            \
                bf16x8 bv = *(const bf16x8*)&w2p[(size_t)((w * 4 + ni) * 32 + (jc)*4 +    \
                                                          ks) *                           \
                                                     512 +                                \
                                                 lane * 8];                               \
                _Pragma("unroll") for (int mi = 0; mi < 4; ++mi)                          \
                    acc2[mi][ni] = __builtin_amdgcn_mfma_f32_16x16x32_bf16(               \
                        am[mi], bv, acc2[mi][ni], 0, 0, 0);                               \
            }                                                                             \
        }                                                                                 \
    }

    FFN_GEMM1(0);
#pragma unroll
    for (int jc = 0; jc < 8; ++jc) {
        __syncthreads();
        if (jc > 0) FFN_GEMM2(jc - 1);
        FFN_WRITE(jc);
        if (jc < 7) FFN_GEMM1(jc + 1);
    }
    __syncthreads();
    FFN_GEMM2(7);
#undef FFN_GEMM1
#undef FFN_WRITE
#undef FFN_GEMM2

#pragma unroll
    for (int mi = 0; mi < 4; ++mi)
#pragma unroll
        for (int ni = 0; ni < 4; ++ni) {
            int col = w * 64 + ni * 16 + l15;
            float bc2 = b2[col];
#pragma unroll
            for (int r = 0; r < 4; ++r) {
                size_t row = (size_t)bm + mi * 16 + l16 * 4 + r;
                out[row * 256 + col] = acc2[mi][ni][r] + bc2 + b2f(xres[row * 256 + col]);
            }
        }
}

// ---------------- Fused slice routing: softmax from L, then stoken = sw^T @ fx via MFMA ----------------
__global__ __launch_bounds__(256) void fused_slice(const short* __restrict__ L,
                                                   const short* __restrict__ fx,
                                                   const float* __restrict__ temp,
                                                   float* __restrict__ stoken,
                                                   float* __restrict__ snorm) {
    int h = blockIdx.y;
    int t0g = blockIdx.x * 2048;
    int b = t0g >> 15;
    int tid = threadIdx.x;
    int lane = tid & 63, w = tid >> 6;
    int l15 = lane & 15, l16 = lane >> 4;
    __shared__ __align__(16) char smem[57344];
    float inv_t = 1.0f / fmaxf(temp[h], 0.1f);
    const int tt2 = tid * 2;
#pragma unroll
    for (int r = 0; r < 16; ++r) {
        int row = 32 + r;
        *(short*)(smem + 32768 + row * 512 + (tt2 ^ ((row & 7) << 4))) =
            (r == 0) ? (short)0x3F80 : (short)0;
    }
    f32x4 acc[4][3] = {};
    const int swz = (l15 & 7) << 4;
    const int abase = l15 * 512;
    for (int sub = 0; sub < 8; ++sub) {
        __syncthreads();
        int t = t0g + sub * 256 + tid;
        float lg[64];
        const short* Lp = &L[(size_t)t * 512 + h * 64];
#pragma unroll
        for (int mv = 0; mv < 8; ++mv) {
            bf16x8 v = *(const bf16x8*)(Lp + mv * 8);
#pragma unroll
            for (int j = 0; j < 8; ++j) lg[mv * 8 + j] = b2f(v[j]) * inv_t;
        }
        float mx = -1e30f;
#pragma unroll
        for (int m = 0; m < 64; ++m) mx = fmaxf(mx, lg[m]);
        float sum = 0.f;
#pragma unroll
        for (int m = 0; m < 64; ++m) { lg[m] = expf(lg[m] - mx); sum += lg[m]; }
        float inv = 1.0f / sum;
#pragma unroll
        for (int m = 0; m < 64; ++m)
            *(short*)(smem + m * 512 + (tt2 ^ ((m & 7) << 4))) = f2b(lg[m] * inv);
        const short* fxp = &fx[(size_t)t * 256 + h * 32];
#pragma unroll
        for (int mv = 0; mv < 4; ++mv) {
            bf16x8 v = *(const bf16x8*)(fxp + mv * 8);
#pragma unroll
            for (int j = 0; j < 8; ++j)
                *(short*)(smem + 32768 + (mv * 8 + j) * 512 + (tt2 ^ (j << 4))) = v[j];
        }
        __syncthreads();
#pragma unroll
        for (int ks = 0; ks < 2; ++ks) {
            int off = ((w * 8 + ks * 4 + l16) * 16) ^ swz;
            bf16x8 a0 = *(const bf16x8*)(smem + abase + off);
            bf16x8 a1 = *(const bf16x8*)(smem + abase + 8192 + off);
            bf16x8 a2 = *(const bf16x8*)(smem + abase + 16384 + off);
            bf16x8 a3 = *(const bf16x8*)(smem + abase + 24576 + off);
            bf16x8 b0 = *(const bf16x8*)(smem + 32768 + abase + off);
            bf16x8 b1 = *(const bf16x8*)(smem + 32768 + abase + 8192 + off);
            bf16x8 b2v = *(const bf16x8*)(smem + 32768 + abase + 16384 + off);
            acc[0][0] = __builtin_amdgcn_mfma_f32_16x16x32_bf16(a0, b0, acc[0][0], 0, 0, 0);
            acc[0][1] = __builtin_amdgcn_mfma_f32_16x16x32_bf16(a0, b1, acc[0][1], 0, 0, 0);
            acc[0][2] = __builtin_amdgcn_mfma_f32_16x16x32_bf16(a0, b2v, acc[0][2], 0, 0, 0);
            acc[1][0] = __builtin_amdgcn_mfma_f32_16x16x32_bf16(a1, b0, acc[1][0], 0, 0, 0);
            acc[1][1] = __builtin_amdgcn_mfma_f32_16x16x32_bf16(a1, b1, acc[1][1], 0, 0, 0);
            acc[1][2] = __builtin_amdgcn_mfma_f32_16x16x32_bf16(a1, b2v, acc[1][2], 0, 0, 0);
            acc[2][0] = __builtin_amdgcn_mfma_f32_16x16x32_bf16(a2, b0, acc[2][0], 0, 0, 0);
            acc[2][1] = __builtin_amdgcn_mfma_f32_16x16x32_bf16(a2, b1, acc[2][1], 0, 0, 0);
            acc[2][2] = __builtin_amdgcn_mfma_f32_16x16x32_bf16(a2, b2v, acc[2][2], 0, 0, 0);
            acc[3][0] = __builtin_amdgcn_mfma_f32_16x16x32_bf16(a3, b0, acc[3][0], 0, 0, 0);
            acc[3][1] = __builtin_amdgcn_mfma_f32_16x16x32_bf16(a3, b1, acc[3][1], 0, 0, 0);
            acc[3][2] = __builtin_amdgcn_mfma_f32_16x16x32_bf16(a3, b2v, acc[3][2], 0, 0, 0);
        }
    }
    __syncthreads();
    float* red = (float*)smem;  // [4 waves][64 m][48 n]
#pragma unroll
    for (int mi = 0; mi < 4; ++mi)
#pragma unroll
        for (int ni = 0; ni < 3; ++ni)
#pragma unroll
            for (int r = 0; r < 4; ++r)
                red[w * 3072 + (mi * 16 + l16 * 4 + r) * 48 + ni * 16 + l15] =
                    acc[mi][ni][r];
    __syncthreads();
    for (int e = tid; e < 3072; e += 256) {
        float s = red[e] + red[3072 + e] + red[6144 + e] + red[9216 + e];
        int m = e / 48, n = e - m * 48;
        if (n < 32)
            atomicAdd(&stoken[(size_t)((b * 8 + h) * 64 + m) * 32 + n], s);
        else if (n == 32)
            atomicAdd(&snorm[(b * 8 + h) * 64 + m], s);
    }
}

// ---------------- Tiny M=64 attention per (b,h): 256 threads, LDS-staged ----------------
__global__ __launch_bounds__(256) void slice_attn_kernel(const float* __restrict__ stoken,
                                                         const float* __restrict__ snorm,
                                                         const float* __restrict__ Wq,
                                                         const float* __restrict__ Wk,
                                                         const float* __restrict__ Wv,
                                                         float* __restrict__ oslice) {
    int bh = blockIdx.x;
    int tid = threadIdx.x;
    int m = tid & 63, grp = tid >> 6;  // 4 groups
    __shared__ float st_s[64][33];
    __shared__ float q_s[64][33];
    __shared__ float k_s[64][33];
    __shared__ float v_s[64][33];
    __shared__ float w_s[3][32][32];
    __shared__ float sc_s[64][65];
    __shared__ float nrm_s[64];
    for (int i = tid; i < 3072; i += 256) {
        const float* W = (i < 1024) ? Wq : (i < 2048 ? Wk : Wv);
        int r = i & 1023;
        w_s[i >> 10][r >> 5][r & 31] = W[r];
    }
    if (tid < 64) nrm_s[tid] = 1.0f / fmaxf(snorm[bh * 64 + tid], 1e-5f);
    for (int i = tid; i < 512; i += 256) {
        int mm = i >> 3, dq = (i & 7) << 2;
        f32x4 v = *(const f32x4*)&stoken[(size_t)bh * 2048 + mm * 32 + dq];
        *(f32x4*)&st_s[mm][dq] = v;
    }
    __syncthreads();
    {
        int d0 = grp * 8;
        float qr[8] = {}, kr[8] = {}, vr[8] = {};
#pragma unroll
        for (int dd = 0; dd < 32; ++dd) {
            float s = st_s[m][dd];
#pragma unroll
            for (int j = 0; j < 8; ++j) {
                qr[j] += s * w_s[0][dd][d0 + j];
                kr[j] += s * w_s[1][dd][d0 + j];
                vr[j] += s * w_s[2][dd][d0 + j];
            }
        }
        float nm = nrm_s[m];
#pragma unroll
        for (int j = 0; j < 8; ++j) {
            q_s[m][d0 + j] = qr[j] * nm;
            k_s[m][d0 + j] = kr[j] * nm;
            v_s[m][d0 + j] = vr[j] * nm;
        }
    }
    __syncthreads();
    {
#pragma unroll
        for (int gg = 0; gg < 16; ++gg) {
            int g = grp * 16 + gg;
            float s = 0.f;
#pragma unroll
            for (int dd = 0; dd < 32; ++dd) s += q_s[m][dd] * k_s[g][dd];
            sc_s[m][g] = s * 0.17677669529663687f;
        }
    }
    __syncthreads();
    if (tid < 64) {
        float mx = -1e30f;
#pragma unroll
        for (int g = 0; g < 64; ++g) mx = fmaxf(mx, sc_s[tid][g]);
        float sum = 0.f;
#pragma unroll
        for (int g = 0; g < 64; ++g) {
            float e = expf(sc_s[tid][g] - mx);
            sc_s[tid][g] = e;
            sum += e;
        }
        float inv = 1.0f / sum;
#pragma unroll
        for (int g = 0; g < 64; ++g) sc_s[tid][g] *= inv;
    }
    __syncthreads();
    {
        int d0 = grp * 8;
        float o[8] = {};
#pragma unroll
        for (int g = 0; g < 64; ++g) {
            float p = sc_s[m][g];
#pragma unroll
            for (int j = 0; j < 8; ++j) o[j] += p * v_s[g][d0 + j];
        }
#pragma unroll
        for (int j = 0; j < 8; ++j)
            oslice[(size_t)bh * 2048 + m * 32 + d0 + j] = o[j];
    }
}

// ---------------- Scatter: y = sw @ oslice via MFMA (round-12 version) ----------------
__global__ __launch_bounds__(256) void scatter_mfma(const short* __restrict__ L,
                                                    const float* __restrict__ oslice,
                                                    const float* __restrict__ temp,
                                                    short* __restrict__ y) {
    int h = blockIdx.y;
    int t0 = blockIdx.x * 256;
    int b = t0 >> 15;
    int tid = threadIdx.x;
    int lane = tid & 63, w = tid >> 6;
    int l15 = lane & 15, l16 = lane >> 4;
    __shared__ __align__(16) char smem[36864];
    float inv_t = 1.0f / fmaxf(temp[h], 0.1f);
    const float* osp = &oslice[(size_t)(b * 8 + h) * 2048];
    for (int i = tid; i < 2048; i += 256) {
        int m = i >> 5, d = i & 31;
        *(short*)(smem + 32768 + d * 128 + ((2 * m) ^ ((d & 7) << 4))) = f2b(osp[m * 32 + d]);
    }
    float lg[64];
    const short* Lp = &L[(size_t)(t0 + tid) * 512 + h * 64];
#pragma unroll
    for (int mv = 0; mv < 8; ++mv) {
        bf16x8 v = *(const bf16x8*)(Lp + mv * 8);
#pragma unroll
        for (int j = 0; j < 8; ++j) lg[mv * 8 + j] = b2f(v[j]) * inv_t;
    }
    float mx = -1e30f;
#pragma unroll
    for (int m = 0; m < 64; ++m) mx = fmaxf(mx, lg[m]);
    float sum = 0.f;
#pragma unroll
    for (int m = 0; m < 64; ++m) { lg[m] = expf(lg[m] - mx); sum += lg[m]; }
    float inv = 1.0f / sum;
    int tswz = (tid & 7) << 4;
#pragma unroll
    for (int jm = 0; jm < 8; ++jm) {
        bf16x8 o;
#pragma unroll
        for (int j = 0; j < 8; ++j) o[j] = f2b(lg[jm * 8 + j] * inv);
        *(bf16x8*)(smem + tid * 128 + ((jm * 16) ^ tswz)) = o;
    }
    __syncthreads();
    const int swz = (l15 & 7) << 4;
    f32x4 acc[4][2] = {};
#pragma unroll
    for (int ks = 0; ks < 2; ++ks) {
        int off = ((ks * 4 + l16) * 16) ^ swz;
        bf16x8 b0 = *(const bf16x8*)(smem + 32768 + l15 * 128 + off);
        bf16x8 b1 = *(const bf16x8*)(smem + 32768 + (16 + l15) * 128 + off);
#pragma unroll
        for (int i = 0; i < 4; ++i) {
            bf16x8 a = *(const bf16x8*)(smem + (w * 64 + i * 16 + l15) * 128 + off);
            acc[i][0] = __builtin_amdgcn_mfma_f32_16x16x32_bf16(a, b0, acc[i][0], 0, 0, 0);
            acc[i][1] = __builtin_amdgcn_mfma_f32_16x16x32_bf16(a, b1, acc[i][1], 0, 0, 0);
        }
    }
#pragma unroll
    for (int i = 0; i < 4; ++i)
#pragma unroll
        for (int ni = 0; ni < 2; ++ni)
#pragma unroll
            for (int r = 0; r < 4; ++r) {
                int tr = w * 64 + i * 16 + l16 * 4 + r;
                y[(size_t)(t0 + tr) * 256 + h * 32 + ni * 16 + l15] = f2b(acc[i][ni][r]);
            }
}

extern "C" void kernel_launch(void* const* d_in, const int* in_sizes, int n_in,
                              void* d_out, int out_size, void* d_ws, size_t ws_size,
                              hipStream_t stream) {
    (void)in_sizes; (void)n_in; (void)out_size; (void)ws_size;
    const float* x    = (const float*)d_in[0];
    const float* ln1g = (const float*)d_in[1];
    const float* ln1b = (const float*)d_in[2];
    const float* Wfx  = (const float*)d_in[3];
    const float* bfx  = (const float*)d_in[4];
    const float* Wx   = (const float*)d_in[5];
    const float* bx   = (const float*)d_in[6];
    const float* Wsl  = (const float*)d_in[7];
    const float* bsl  = (const float*)d_in[8];
    const float* temp = (const float*)d_in[9];
    const float* Wq   = (const float*)d_in[10];
    const float* Wk   = (const float*)d_in[11];
    const float* Wv   = (const float*)d_in[12];
    const float* Wo   = (const float*)d_in[13];
    const float* bo   = (const float*)d_in[14];
    const float* ln2g = (const float*)d_in[15];
    const float* ln2b = (const float*)d_in[16];
    const float* W1   = (const float*)d_in[17];
    const float* b1   = (const float*)d_in[18];
    const float* W2   = (const float*)d_in[19];
    const float* b2   = (const float*)d_in[20];
    float* out = (float*)d_out;

    constexpr size_t SLOT = (size_t)kT * kC * 2;  // 32MB
    char* ws = (char*)d_ws;
    short* S0 = (short*)(ws);             // h -> y -> h2
    short* S1 = (short*)(ws + SLOT);      // fx -> xres
    char*  S3 = ws + 3 * SLOT;
    short* wfx_t  = (short*)(S3);                // 256 x 256
    short* wxsl_t = (short*)(S3 + 131072);       // 512 x 256 (contiguous -> 768x256)
    short* wo_t   = (short*)(S3 + 393216);       // 256 x 256
    short* w1_t   = (short*)(S3 + 524288);       // 1024 x 256
    short* w2_t   = (short*)(S3 + 1048576);      // 256 x 1024
    float* bxsl   = (float*)(S3 + 1572864);      // 512
    float* stoken = (float*)(S3 + 1574912);      // (B,H,M,D)
    float* snorm  = (float*)(S3 + 1705984);      // (B,H,M)
    float* oslice = (float*)(S3 + 1710080);      // (B,H,M,D)
    short* w1p    = (short*)(S3 + 1841152);      // packed 1024x256
    short* w2p    = (short*)(S3 + 2365440);      // packed 256x1024

    short* h    = S0;
    short* fx   = S1;
    short* y    = S0;
    short* xres = S1;
    short* h2   = S0;
    short* Lbuf = (short*)d_out;  // T x 512 bf16 logits (dead before ffn_fused writes d_out)

    // 0. weight prep (+ fragment packing)
    prep_wt<<<dim3(8, 8), 256, 0, stream>>>(Wfx, wfx_t, 256, 256);
    prep_wt<<<dim3(8, 8), 256, 0, stream>>>(Wo, wo_t, 256, 256);
    prep_wt<<<dim3(8, 32), 256, 0, stream>>>(W1, w1_t, 256, 1024);
    prep_wt<<<dim3(32, 8), 256, 0, stream>>>(W2, w2_t, 1024, 256);
    prep_wxsl<<<512, 256, 0, stream>>>(Wx, Wsl, bx, bsl, wxsl_t, bxsl);
    prep_pack<<<128, 256, 0, stream>>>(w1_t, w1p, 256, 8);    // N=1024, KT=8
    prep_pack<<<128, 256, 0, stream>>>(w2_t, w2p, 1024, 32);  // N=256,  KT=32
    hipMemsetAsync(stoken, 0, 131072 + 4096, stream);

    // 1. LN1: x -> h
    ln_kernel<false><<<kT / 4, 256, 0, stream>>>(x, ln1g, ln1b, h);
    // 2. merged projection: [fx | L] = h @ [Wfx ; Wxsl] (coalesced bf16 writes)
    proj_dual<<<dim3(kT / 128, 6), 256, 0, stream>>>(h, wfx_t, bfx, bxsl, fx, Lbuf);
    // 3. fused slice routing
    fused_slice<<<dim3(kT / 2048, kH), 256, 0, stream>>>(Lbuf, fx, temp, stoken, snorm);
    // 4. tiny attention over M slices
    slice_attn_kernel<<<kB * kH, 256, 0, stream>>>(stoken, snorm, Wq, Wk, Wv, oslice);
    // 5. scatter back to tokens via MFMA -> y
    scatter_mfma<<<dim3(kT / 256, kH), 256, 0, stream>>>(Lbuf, oslice, temp, y);
    // 6. Wo projection + residual(x f32) -> xres (coalesced bf16 writes)
    wo_gemm<<<dim3(kT / 128, 2), 256, 0, stream>>>(y, wo_t, bo, x, xres);
    // 7. LN2: xres -> h2
    ln_kernel<true><<<kT / 4, 256, 0, stream>>>(xres, ln2g, ln2b, h2);
    // 8. fused FFN (round-12 pipelined version)
    ffn_fused<<<kT / 64, 256, 0, stream>>>(h2, xres, w1p, w2p, b1, b2, out);
}